// Round 1
// baseline (172.037 us; speedup 1.0000x reference)
//
#include <hip/hip_runtime.h>

// Grossberg shunting ODE, 127 Euler steps, BATCH=32768, N=17.
// Strategy: 4 lanes per batch item, W_pos/W_neg register-resident
// (<=170 VGPR/lane), state replicated across the 4-lane group via
// __shfl(width=4) each step. One scheduling round: 2048 waves = 2/SIMD.

static constexpr int BATCH = 32768;
static constexpr int NN = 17;
static constexpr int TT = 128;

__global__ __launch_bounds__(256, 2) void hotco_kernel(
    const float* __restrict__ state0,
    const float* __restrict__ Wpos,
    const float* __restrict__ Wneg,
    const float* __restrict__ feas,
    const float* __restrict__ P,
    const float* __restrict__ t_eval,
    float* __restrict__ out)
{
    const int tid = blockIdx.x * blockDim.x + threadIdx.x;
    const int lane4 = tid & 3;
    const int b = tid >> 2;
    if (b >= BATCH) return;

    // lane 0: rows 0-4 (needs), lane 1: rows 5-8 (needs),
    // lane 2: rows 9-12 (acts), lane 3: rows 13-16 (vals)
    const int base = (lane4 == 0) ? 0 : (4 * lane4 + 1);
    const int nrows = (lane4 == 0) ? 5 : 4;

    // ---- W into registers (compile-time indexed only) ----
    float wp[5][17], wn[5][17];
    {
        const float* wpb = Wpos + (size_t)b * (NN * NN);
        const float* wnb = Wneg + (size_t)b * (NN * NN);
#pragma unroll
        for (int t = 0; t < 5; ++t) {
            if (t < nrows) {
                const float* rp = wpb + (base + t) * NN;
                const float* rn = wnb + (base + t) * NN;
#pragma unroll
                for (int j = 0; j < NN; ++j) { wp[t][j] = rp[j]; wn[t][j] = rn[j]; }
            } else {
#pragma unroll
                for (int j = 0; j < NN; ++j) { wp[t][j] = 0.f; wn[t][j] = 0.f; }
            }
        }
    }

    // ---- replicated state + own-slot state ----
    float s[17];
#pragma unroll
    for (int j = 0; j < NN; ++j) s[j] = state0[(size_t)b * NN + j];

    float sOwn[5];
#pragma unroll
    for (int t = 0; t < 5; ++t)
        sOwn[t] = (t < nrows) ? state0[(size_t)b * NN + base + t] : 0.f;

    // ---- per-lane-class slot constants ----
    // needs lanes (0,1): cA = relu(P_e), cB = relu(-P_e)
    // acts lane  (2)   : cA = feasibility, cB = P[13+t] (for gates)
    // vals lane  (3)   : cA = P[13+t] (direct drive), cB unused
    float cA[5], cB[5];
    if (lane4 < 2) {
#pragma unroll
        for (int t = 0; t < 5; ++t) {
            float pv = P[(size_t)b * NN + base + t];
            cA[t] = fmaxf(pv, 0.f);
            cB[t] = fmaxf(-pv, 0.f);
        }
    } else if (lane4 == 2) {
#pragma unroll
        for (int t = 0; t < 4; ++t) {
            cA[t] = feas[(size_t)b * 4 + t];
            cB[t] = P[(size_t)b * NN + 13 + t];
        }
        cA[4] = 0.f; cB[4] = 0.f;
    } else {
#pragma unroll
        for (int t = 0; t < 4; ++t) {
            cA[t] = P[(size_t)b * NN + 13 + t];
            cB[t] = 0.f;
        }
        cA[4] = 0.f; cB[4] = 0.f;
    }

    const float lo = (lane4 == 3) ? -1.f : 0.f;
    const float dt = t_eval[1] - t_eval[0];
    const float k1 = dt / 0.8f;  // dt / TAU

    // ---- write step 0 (= state0) ----
    {
        float* op = out + (size_t)b * NN + base;
#pragma unroll
        for (int t = 0; t < 5; ++t)
            if (t < nrows) op[t] = sOwn[t];
    }

    float* outp = out + (size_t)BATCH * NN + (size_t)b * NN + base;

#pragma unroll 1
    for (int st = 1; st < TT; ++st) {
        // ---- two 17x17 matvec slices (the hot 170 FMAs) ----
        float E5[5], I5[5];
#pragma unroll
        for (int t = 0; t < 5; ++t) {
            float ae = 0.f, ai = 0.f;
#pragma unroll
            for (int j = 0; j < NN; ++j) {
                ae = fmaf(wp[t][j], s[j], ae);
                ai = fmaf(wn[t][j], s[j], ai);
            }
            E5[t] = ae; I5[t] = ai;
        }

        // ---- class-specific transform (lane-uniform branches) ----
        if (lane4 == 2) {
            // acts: gating sigmoids + feasibility + lateral inhibition
            const float sum_acts = s[9] + s[10] + s[11] + s[12];
#pragma unroll
            for (int t = 0; t < 4; ++t) {
                float v  = s[13 + t] + cB[t];
                float ge = __builtin_amdgcn_rcpf(1.f + __expf(-1.5f * v));
                float gi = __builtin_amdgcn_rcpf(1.f + __expf(0.75f * v));
                float E  = fmaxf(ge * E5[t], 0.f) * cA[t];
                float os = sum_acts - s[9 + t];
                float lat = 3.0f * os * __builtin_amdgcn_rcpf(0.3f + os);
                float I  = fmaxf(gi * I5[t], 0.f) + lat;
                E5[t] = E; I5[t] = I;
            }
            E5[4] = 0.f; I5[4] = 0.f;
        } else if (lane4 == 3) {
            // vals: plain relu
#pragma unroll
            for (int t = 0; t < 5; ++t) {
                E5[t] = fmaxf(E5[t], 0.f);
                I5[t] = fmaxf(I5[t], 0.f);
            }
        } else {
            // needs: relu + perturbation split
#pragma unroll
            for (int t = 0; t < 5; ++t) {
                E5[t] = fmaxf(E5[t], 0.f) + cA[t];
                I5[t] = fmaxf(I5[t], 0.f) + cB[t];
            }
        }

        // ---- shunting update + clip ----
        float ns[5];
#pragma unroll
        for (int t = 0; t < 5; ++t) {
            float so = sOwn[t];
            float pd = 0.f;
            if (t < 4) pd = (lane4 == 3) ? cA[t] : 0.f;  // P_direct on vals
            float ds = fmaf(1.0f - so, E5[t], -0.15f * so)
                     - (0.1f + so) * I5[t] + pd;
            float raw = fmaf(k1, ds, so);
            ns[t] = fminf(fmaxf(raw, lo), 1.f);
            sOwn[t] = ns[t];
        }

        // ---- replicate new state across the 4-lane group ----
#pragma unroll
        for (int j = 0; j < NN; ++j) {
            const int k = (j < 5) ? 0 : (j < 9) ? 1 : (j < 13) ? 2 : 3;
            const int c = (j < 5) ? j : (j < 9) ? (j - 5) : (j < 13) ? (j - 9) : (j - 13);
            s[j] = __shfl(ns[c], k, 4);
        }

        // ---- store this step's state ----
#pragma unroll
        for (int t = 0; t < 5; ++t)
            if (t < nrows) outp[t] = ns[t];
        outp += (size_t)BATCH * NN;
    }
}

extern "C" void kernel_launch(void* const* d_in, const int* in_sizes, int n_in,
                              void* d_out, int out_size, void* d_ws, size_t ws_size,
                              hipStream_t stream) {
    const float* state0 = (const float*)d_in[0];
    const float* Wpos   = (const float*)d_in[1];
    const float* Wneg   = (const float*)d_in[2];
    const float* feasv  = (const float*)d_in[3];
    const float* P      = (const float*)d_in[4];
    const float* t_eval = (const float*)d_in[5];
    float* out = (float*)d_out;

    dim3 grid(BATCH * 4 / 256), block(256);
    hipLaunchKernelGGL(hotco_kernel, grid, block, 0, stream,
                       state0, Wpos, Wneg, feasv, P, t_eval, out);
}

// Round 3
// 147.590 us; speedup vs baseline: 1.1656x; 1.1656x over previous
//
#include <hip/hip_runtime.h>
#include <stdint.h>

// Grossberg shunting ODE, 127 Euler steps, BATCH=32768, N=17.
// 4 lanes per item; W register-resident as packed f16 pairs (dot2);
// state replicated as 9 packed u32 via __shfl(width=4).

typedef _Float16 h2 __attribute__((ext_vector_type(2)));
typedef __fp16 h2raw __attribute__((ext_vector_type(2)));

static constexpr int BATCH = 32768;
static constexpr int NN = 17;
static constexpr int TT = 128;

__device__ __forceinline__ uint32_t pk(float a, float b) {
    h2raw h = __builtin_amdgcn_cvt_pkrtz(a, b);
    return __builtin_bit_cast(uint32_t, h);
}

__device__ __forceinline__ float dot2(uint32_t a, uint32_t b, float c) {
#if __has_builtin(__builtin_amdgcn_fdot2)
    return __builtin_amdgcn_fdot2(__builtin_bit_cast(h2, a),
                                  __builtin_bit_cast(h2, b), c, false);
#else
    h2 ah = __builtin_bit_cast(h2, a), bh = __builtin_bit_cast(h2, b);
    return c + (float)ah.x * (float)bh.x + (float)ah.y * (float)bh.y;
#endif
}

__global__ __launch_bounds__(256, 2) void hotco_kernel(
    const float* __restrict__ state0,
    const float* __restrict__ Wpos,
    const float* __restrict__ Wneg,
    const float* __restrict__ feas,
    const float* __restrict__ P,
    const float* __restrict__ t_eval,
    float* __restrict__ out)
{
    const int tid = blockIdx.x * blockDim.x + threadIdx.x;
    const int lane4 = tid & 3;
    const int b = tid >> 2;
    if (b >= BATCH) return;

    // lane0: rows 0-4 (needs), lane1: 5-8 (needs), lane2: 9-12 (acts), lane3: 13-16 (vals)
    const int base = (lane4 == 0) ? 0 : (4 * lane4 + 1);
    const int nrows = (lane4 == 0) ? 5 : 4;

    // pair grouping of the 17-vector into 9 u32 (class-aligned):
    // c: 0:(0,1) 1:(2,3) 2:(4,-) 3:(5,6) 4:(7,8) 5:(9,10) 6:(11,12) 7:(13,14) 8:(15,16)
    constexpr int pA[9] = {0, 2, 4, 5, 7, 9, 11, 13, 15};
    constexpr int pB[9] = {1, 3, -1, 6, 8, 10, 12, 14, 16};

    // ---- W into registers, packed f16 pairs ----
    uint32_t wp[5][9], wn[5][9];
    {
        const float* wpb = Wpos + (size_t)b * (NN * NN);
        const float* wnb = Wneg + (size_t)b * (NN * NN);
#pragma unroll
        for (int t = 0; t < 5; ++t) {
            if (t < nrows) {
                const float* rp = wpb + (base + t) * NN;
                const float* rn = wnb + (base + t) * NN;
#pragma unroll
                for (int c = 0; c < 9; ++c) {
                    float a2 = (pB[c] < 0) ? 0.f : rp[pB[c]];
                    float b2 = (pB[c] < 0) ? 0.f : rn[pB[c]];
                    wp[t][c] = pk(rp[pA[c]], a2);
                    wn[t][c] = pk(rn[pA[c]], b2);
                }
            } else {
#pragma unroll
                for (int c = 0; c < 9; ++c) { wp[t][c] = 0u; wn[t][c] = 0u; }
            }
        }
    }

    // ---- initial state: replicated packed + own f32 ----
    uint32_t s2[9];
    {
        float st[17];
#pragma unroll
        for (int j = 0; j < NN; ++j) st[j] = state0[(size_t)b * NN + j];
#pragma unroll
        for (int c = 0; c < 9; ++c)
            s2[c] = pk(st[pA[c]], (pB[c] < 0) ? 0.f : st[pB[c]]);
    }
    float sOwn[5];
#pragma unroll
    for (int t = 0; t < 5; ++t)
        sOwn[t] = (t < nrows) ? state0[(size_t)b * NN + base + t] : 0.f;

    // ---- per-lane-class constants ----
    float aE[5], aI[5], pdv[5];   // non-acts adds / vals direct drive
    float gP[4], gF[4];           // acts: gate perturbation, feasibility
#pragma unroll
    for (int t = 0; t < 5; ++t) { aE[t] = 0.f; aI[t] = 0.f; pdv[t] = 0.f; }
#pragma unroll
    for (int t = 0; t < 4; ++t) { gP[t] = 0.f; gF[t] = 0.f; }
    if (lane4 < 2) {
#pragma unroll
        for (int t = 0; t < 5; ++t) {
            if (t < nrows) {
                float pv = P[(size_t)b * NN + base + t];
                aE[t] = fmaxf(pv, 0.f);
                aI[t] = fmaxf(-pv, 0.f);
            }
        }
    } else if (lane4 == 2) {
#pragma unroll
        for (int t = 0; t < 4; ++t) {
            gP[t] = P[(size_t)b * NN + 13 + t];
            gF[t] = feas[(size_t)b * 4 + t];
        }
    } else {
#pragma unroll
        for (int t = 0; t < 4; ++t)
            pdv[t] = P[(size_t)b * NN + 13 + t];
    }

    const float lo = (lane4 == 3) ? -1.f : 0.f;
    const float dt = t_eval[1] - t_eval[0];
    const float k1 = dt / 0.8f;                   // dt / TAU
    const float C  = -1.0820212806667226f;        // -0.75 * log2(e)

    // ---- write step 0 ----
    {
        float* op = out + (size_t)b * NN + base;
#pragma unroll
        for (int t = 0; t < 5; ++t)
            if (t < nrows) op[t] = sOwn[t];
    }
    float* outp = out + (size_t)BATCH * NN + (size_t)b * NN + base;

#pragma unroll 1
    for (int st = 1; st < TT; ++st) {
        // ---- matvec: 2 x (5 rows x 9 dot2) ----
        float E5[5], I5[5];
#pragma unroll
        for (int t = 0; t < 5; ++t) {
            float ae = 0.f, ai = 0.f;
#pragma unroll
            for (int c = 0; c < 9; ++c) {
                ae = dot2(wp[t][c], s2[c], ae);
                ai = dot2(wn[t][c], s2[c], ai);
            }
            E5[t] = fmaxf(ae, 0.f);   // uniform relu (relu(g*x) = g*relu(x), g>0)
            I5[t] = fmaxf(ai, 0.f);
        }

        // ---- class transform ----
        if (lane4 == 2) {
            const float sum_acts = sOwn[0] + sOwn[1] + sOwn[2] + sOwn[3];
            h2 q7 = __builtin_bit_cast(h2, s2[7]);
            h2 q8 = __builtin_bit_cast(h2, s2[8]);
            float v13[4] = { (float)q7.x, (float)q7.y, (float)q8.x, (float)q8.y };
#pragma unroll
            for (int t = 0; t < 4; ++t) {
                float v  = v13[t] + gP[t];
                float e1 = __builtin_amdgcn_exp2f(C * v);     // e^(-0.75 v)
                float ge = __builtin_amdgcn_rcpf(fmaf(e1, e1, 1.f));   // sigmoid(1.5v)
                float gi = e1 * __builtin_amdgcn_rcpf(1.f + e1);       // sigmoid(-0.75v)
                E5[t] = ge * E5[t] * gF[t];
                float os  = sum_acts - sOwn[t];
                float lat = fmaf(-0.9f, __builtin_amdgcn_rcpf(0.3f + os), 3.0f);
                I5[t] = fmaf(gi, I5[t], lat);
            }
            E5[4] = 0.f; I5[4] = 0.f;
        } else {
#pragma unroll
            for (int t = 0; t < 5; ++t) { E5[t] += aE[t]; I5[t] += aI[t]; }
        }

        // ---- shunting update + clip ----
#pragma unroll
        for (int t = 0; t < 5; ++t) {
            float s  = sOwn[t];
            float d0 = fmaf(-0.15f, s, pdv[t]);
            float d1 = fmaf(1.f - s, E5[t], d0);
            float d2 = fmaf(-(0.1f + s), I5[t], d1);
            float raw = fmaf(k1, d2, s);
            sOwn[t] = fminf(fmaxf(raw, lo), 1.f);
        }

        // ---- pack own slots, replicate across 4-lane group ----
        uint32_t pk0 = pk(sOwn[0], sOwn[1]);
        uint32_t pk1 = pk(sOwn[2], sOwn[3]);
        uint32_t pk2 = pk(sOwn[4], 0.f);
        s2[0] = (uint32_t)__shfl((int)pk0, 0, 4);
        s2[1] = (uint32_t)__shfl((int)pk1, 0, 4);
        s2[2] = (uint32_t)__shfl((int)pk2, 0, 4);
        s2[3] = (uint32_t)__shfl((int)pk0, 1, 4);
        s2[4] = (uint32_t)__shfl((int)pk1, 1, 4);
        s2[5] = (uint32_t)__shfl((int)pk0, 2, 4);
        s2[6] = (uint32_t)__shfl((int)pk1, 2, 4);
        s2[7] = (uint32_t)__shfl((int)pk0, 3, 4);
        s2[8] = (uint32_t)__shfl((int)pk1, 3, 4);

        // ---- store ----
#pragma unroll
        for (int t = 0; t < 5; ++t)
            if (t < nrows) outp[t] = sOwn[t];
        outp += (size_t)BATCH * NN;
    }
}

extern "C" void kernel_launch(void* const* d_in, const int* in_sizes, int n_in,
                              void* d_out, int out_size, void* d_ws, size_t ws_size,
                              hipStream_t stream) {
    const float* state0 = (const float*)d_in[0];
    const float* Wpos   = (const float*)d_in[1];
    const float* Wneg   = (const float*)d_in[2];
    const float* feasv  = (const float*)d_in[3];
    const float* P      = (const float*)d_in[4];
    const float* t_eval = (const float*)d_in[5];
    float* out = (float*)d_out;

    dim3 grid(BATCH * 4 / 256), block(256);
    hipLaunchKernelGGL(hotco_kernel, grid, block, 0, stream,
                       state0, Wpos, Wneg, feasv, P, t_eval, out);
}